// Round 9
// baseline (284.267 us; speedup 1.0000x reference)
//
#include <hip/hip_runtime.h>
#include <math.h>

#define IMG_H 1024
#define IMG_W 1024
#define IMG_B 8
#define TPB 1024                   // 1024 thr * 1 px = one full row
#define RPB 16                     // output rows per band
#define BANDS (IMG_H / RPB)        // 64
#define NBLK (IMG_B * BANDS)       // 512 blocks = 2/CU

__device__ __forceinline__ float sig2(float x) {   // sigmoid(2x) == sigmoid(x/EPS)
    return 1.0f / (1.0f + __expf(-2.0f * x));
}
__device__ __forceinline__ int imax(int a, int b) { return a > b ? a : b; }
__device__ __forceinline__ int imin(int a, int b) { return a < b ? a : b; }

// ---------------------------------------------------------------------------
// Skew-2 depth-D pipeline: level l processes row s_l = y - 2*l at step y.
// Because each level lags its producer by TWO rows, every q-stage input
// (uY/uZ register history, su x-neighbor) was produced in a PREVIOUS step:
// all levels are independent within a step.
//   phase A: all q-stages (q_l[s_l] from u_{l-1} history) + p0/p1 + sp writes
//   barrier
//   phase B: all u-stages (u_l = sig2(o - Tq_l)) + su writes  [+ FINAL out]
//   barrier (sp write-after-read for next step)
// => 2 barriers/step instead of 6, and all LDS reads / exp chains in a phase
// overlap via ILP instead of serializing.
// o/vf are re-read per level from cache (uniform row => SALU addressing;
// rows are L1/L2 resident across the ~6 consuming steps).
// Hazard audit: su[l] is row-parity double buffered; read of row t (parity p)
// at step y happens before the same-parity write of row t+2 (phase B, same
// step) -- fenced by the mid barrier; write at step y vs read at step y+2 is
// fenced by step y+1's barriers. sp[l] read (phase B) vs next write (phase A,
// y+1) is fenced by the end barrier.
// Validity bounds per level are IDENTICAL to the R4-verified lineage:
//   qlo_l = max(r0-(D-l)-HALO,0), ulo_l = qlo_{l+1}, u0lo = qlo_1 - ... etc.
// ---------------------------------------------------------------------------
template<int D, bool READQ, bool FINAL>
__global__ __launch_bounds__(TPB, 8) void k_pipe(const float* __restrict__ qin,
                                                 const float* __restrict__ vf,
                                                 const float* __restrict__ o,
                                                 float* __restrict__ out) {
    __shared__ float sp[D + 1][TPB + 1];   // p0 boundary, per level
    __shared__ float su[D][2][TPB + 1];    // u rows, row-parity

    const int img = blockIdx.x / BANDS;
    const int r0  = (blockIdx.x % BANDS) * RPB;
    const int tid = threadIdx.x;
    const size_t ibase = (size_t)img * IMG_H * IMG_W;

    if (tid == 0) {
#pragma unroll
        for (int l = 0; l <= D; ++l) sp[l][0] = 0.0f;
#pragma unroll
        for (int l = 0; l < D; ++l) { su[l][0][TPB] = 0.0f; su[l][1][TPB] = 0.0f; }
    }

    constexpr int HALO = FINAL ? 1 : 0;
    const int u0lo = imax(r0 - (D - 1) - HALO, 0);
    const int ylo  = READQ ? imax(r0 - D - HALO, 0) : u0lo;
    const int yend = r0 + RPB - 1 + 2 * D;

    float uY[D], uZ[D];        // u_l at rows s_l+1, s_l (own history)
    float p1prev[D + 1];       // p1 of q_l at previous row
    float qs1[D], qs2[D];      // q_l one / two steps ago (l = 0..D-1)

#pragma unroll
    for (int l = 0; l < D; ++l) { uY[l] = 0.0f; uZ[l] = 0.0f; qs1[l] = 0.0f; qs2[l] = 0.0f; }
#pragma unroll
    for (int l = 0; l <= D; ++l) p1prev[l] = 0.0f;

    for (int y = ylo; y <= yend; ++y) {
        float p0s[D + 1], p1s[D + 1], ot[D + 1];

        // ---------------- phase A: all q-stages ----------------
        float qc = 0.0f;
        {
            const int yc = imin(y, IMG_H - 1);
            ot[0] = o[ibase + (size_t)yc * IMG_W + tid];
            if constexpr (READQ) {
                const float q0 = qin[ibase + (size_t)yc * IMG_W + tid];
                const float2 v2 = *(const float2*)(vf + ((size_t)yc * IMG_W + tid) * 2);
                qc = (y <= IMG_H - 1) ? q0 : 0.0f;
                p0s[0] = v2.x * qc;
                p1s[0] = v2.y * qc;
                sp[0][tid + 1] = p0s[0];
            }
        }
        float qvPrev = 0.0f;
#pragma unroll
        for (int l = 1; l <= D; ++l) {
            const int t  = y - 2 * l;
            const int tc = imin(imax(t, 0), IMG_H - 1);
            const int qlo = imax(r0 - (D - l) - HALO, 0);
            const bool qvalid = (t >= qlo) && (t <= IMG_H - 1);

            const float qb = qs2[l - 1];                 // q_{l-1}[t], 2 steps old
            qs2[l - 1] = qs1[l - 1];
            qs1[l - 1] = (l == 1) ? qc : qvPrev;

            const float2 vt = *(const float2*)(vf + ((size_t)tc * IMG_W + tid) * 2);
            const float uR = su[l - 1][t & 1][tid + 1];  // u_{l-1}[t][x+1], fenced
            const float gy = uY[l - 1] - uZ[l - 1];      // u[t+1]-u[t]
            const float gx = uR - uZ[l - 1];             // u[t][x+1]-u[t][x]
            const float qv = qvalid
                ? fmaxf(qb - 0.5f * (gy * vt.y + gx * vt.x), 0.0f) : 0.0f;

            if (l < D || FINAL) {
                p0s[l] = vt.x * qv;
                p1s[l] = vt.y * qv;
                sp[l][tid + 1] = p0s[l];
                ot[l] = o[ibase + (size_t)tc * IMG_W + tid];
            } else {                                     // init launch: emit q_D
                if (t >= r0 && t < r0 + RPB)
                    out[ibase + (size_t)t * IMG_W + tid] = qv;
            }
            qvPrev = qv;
        }
        __syncthreads();                                 // A -> B

        // ---------------- phase B: all u-stages ----------------
        if constexpr (READQ) {
            if (y >= u0lo) {
                const float pm1 = sp[0][tid];
                const float nu = (y <= IMG_H - 1)
                    ? sig2(ot[0] - (p1s[0] - p1prev[0] + p0s[0] - pm1)) : 0.0f;
                uZ[0] = uY[0]; uY[0] = nu;
                su[0][y & 1][tid] = nu;
            }
            p1prev[0] = p1s[0];
        } else {
            const float nu = (y <= IMG_H - 1) ? sig2(ot[0]) : 0.0f;
            uZ[0] = uY[0]; uY[0] = nu;
            su[0][y & 1][tid] = nu;
        }
#pragma unroll
        for (int l = 1; l < D; ++l) {
            const int t = y - 2 * l;
            const int ulo = imax(r0 - (D - 1 - l) - HALO, 0);
            if (t >= ulo) {
                const float pm1 = sp[l][tid];
                const float nu = (t <= IMG_H - 1)
                    ? sig2(ot[l] - (p1s[l] - p1prev[l] + p0s[l] - pm1)) : 0.0f;
                uZ[l] = uY[l]; uY[l] = nu;
                su[l][t & 1][tid] = nu;
            }
            p1prev[l] = p1s[l];
        }
        if constexpr (FINAL) {
            const int t = y - 2 * D;
            if (t >= r0 && t < r0 + RPB) {
                const float pm1 = sp[D][tid];
                const float Tq = p1s[D] - p1prev[D] + p0s[D] - pm1;
                out[ibase + (size_t)t * IMG_W + tid] = 2.0f * (ot[D] - Tq);
            }
            p1prev[D] = p1s[D];
        }
        __syncthreads();                                 // sp WAR fence
    }
}

extern "C" void kernel_launch(void* const* d_in, const int* in_sizes, int n_in,
                              void* d_out, int out_size, void* d_ws, size_t ws_size,
                              hipStream_t stream) {
    const float* o  = (const float*)d_in[0];
    const float* vf = (const float*)d_in[1];
    float* qA = (float*)d_ws;

    // iterations 1..5: o,vf -> q5  (no q read)
    k_pipe<5, false, false><<<NBLK, TPB, 0, stream>>>(o, vf, o, qA);
    // iterations 6..10 + final: q5,o,vf -> out
    k_pipe<5, true,  true ><<<NBLK, TPB, 0, stream>>>(qA, vf, o, (float*)d_out);
}

// Round 10
// 216.158 us; speedup vs baseline: 1.3151x; 1.3151x over previous
//
#include <hip/hip_runtime.h>
#include <math.h>

#define IMG_H 1024
#define IMG_W 1024
#define IMG_B 8
#define TPB 1024                   // 1024 thr * 1 px = one full row
#define RPB 16                     // output rows per band
#define BANDS (IMG_H / RPB)        // 64
#define NBLK (IMG_B * BANDS)       // 512 blocks = 2/CU = 32 waves/CU

__device__ __forceinline__ float sig2(float x) {   // sigmoid(2x) == sigmoid(x/EPS)
    return 1.0f / (1.0f + __expf(-2.0f * x));
}
__device__ __forceinline__ int imax(int a, int b) { return a > b ? a : b; }
__device__ __forceinline__ int imin(int a, int b) { return a < b ? a : b; }

// Force a value to be materialized (and kept) in a VGPR: defeats the
// compiler's rematerialize-the-load heuristic (R4 ran at VGPR_Count=32 with
// >=39 live history floats -- the history was being re-loaded per level).
#define PIN(x) asm volatile("" : "+v"(x))

// ---------------------------------------------------------------------------
// Depth-D row-pipelined kernel, 1 px/thread, 2 blocks/CU * 16 waves = 100% occ.
//   READQ: level-0 u = sig2(o - Tq(qin)); else u0 = sig2(o)  (q0 = 0).
//   FINAL: after Q-stage D, write out = 2*(o - Tq(q^D)) instead of q^D.
// Identical structure to the Round-4 kernel (best so far); the ONLY change
// is the register pinning of per-thread history state.
// ---------------------------------------------------------------------------
template<int D, bool READQ, bool FINAL>
__global__ __launch_bounds__(TPB, 8) void k_pipe(const float* __restrict__ qin,
                                                 const float* __restrict__ vf,
                                                 const float* __restrict__ o,
                                                 float* __restrict__ out) {
    __shared__ float sp[2][TPB + 1];       // p0 boundary, level-parity
    __shared__ float su[D][2][TPB + 1];    // u rows, row-parity

    const int img = blockIdx.x / BANDS;
    const int r0  = (blockIdx.x % BANDS) * RPB;
    const int tid = threadIdx.x;
    const size_t ibase = (size_t)img * IMG_H * IMG_W;

    if (tid == 0) {
        sp[0][0] = 0.0f; sp[1][0] = 0.0f;
#pragma unroll
        for (int l = 0; l < D; ++l) { su[l][0][TPB] = 0.0f; su[l][1][TPB] = 0.0f; }
    }

    constexpr int HALO = FINAL ? 1 : 0;
    constexpr int NOH  = FINAL ? D + 1 : D;

    const int u0lo = imax(r0 - (D - 1) - HALO, 0);
    const int ylo  = READQ ? imax(r0 - D - HALO, 0) : u0lo;
    const int yend = r0 + RPB - 1 + D;
    const int yhi  = imin(yend, IMG_H - 1);

    float qc = 0.0f, qz = 0.0f;            // q^0 rows y, y-1
    float oh[NOH];                         // o rows y-l
    float v0h[D + 1], v1h[D + 1];          // vf rows y-l
    float uY[D], uZ[D];                    // u^l rows y-l, y-l-1
    float p1prev[D + 1];                   // p1 of q^l at previous row
    float qsave[D];                        // q^l held one step for level l+1
    float qvPrev = 0.0f;

#pragma unroll
    for (int l = 0; l < NOH; ++l) oh[l] = 0.0f;
#pragma unroll
    for (int l = 0; l <= D; ++l) { v0h[l] = 0.0f; v1h[l] = 0.0f; p1prev[l] = 0.0f; }
#pragma unroll
    for (int l = 0; l < D; ++l) { uY[l] = 0.0f; uZ[l] = 0.0f; qsave[l] = 0.0f; }

    const float* pQ = qin + ibase + (size_t)ylo * IMG_W + tid;
    const float* pO = o   + ibase + (size_t)ylo * IMG_W + tid;
    const float* pV = vf  + ((size_t)ylo * IMG_W + tid) * 2;

    for (int y = ylo; y <= yend; ++y) {
        // ---- shift row histories, then load row y ----
#pragma unroll
        for (int k = NOH - 1; k >= 1; --k) oh[k] = oh[k - 1];
#pragma unroll
        for (int k = D; k >= 1; --k) { v0h[k] = v0h[k - 1]; v1h[k] = v1h[k - 1]; }
        if constexpr (READQ) qz = qc;

        if (y <= yhi) {
            if constexpr (READQ) { qc = *pQ; pQ += IMG_W; }
            oh[0] = *pO; pO += IMG_W;
            float2 v2 = *(const float2*)pV; pV += 2 * IMG_W;
            v0h[0] = v2.x; v1h[0] = v2.y;
        } else {
            qc = 0.0f; oh[0] = 0.0f; v0h[0] = 0.0f; v1h[0] = 0.0f;
        }

        // ---- pin the full per-thread state into VGPRs (no runtime cost) ----
#pragma unroll
        for (int k = 0; k < NOH; ++k) PIN(oh[k]);
#pragma unroll
        for (int k = 0; k <= D; ++k) { PIN(v0h[k]); PIN(v1h[k]); PIN(p1prev[k]); }
#pragma unroll
        for (int k = 0; k < D; ++k) { PIN(uY[k]); PIN(uZ[k]); PIN(qsave[k]); }
        if constexpr (READQ) { PIN(qc); PIN(qz); }

        // ---- level 0 ----
        if constexpr (READQ) {
            float p0c = v0h[0] * qc;
            float p1c = v1h[0] * qc;
            sp[0][tid + 1] = p0c;
            __syncthreads();                       // barrier level 0
            if (y >= u0lo) {
                float pm1 = sp[0][tid];
                float nu = (y <= IMG_H - 1)
                    ? sig2(oh[0] - (p1c - p1prev[0] + p0c - pm1)) : 0.0f;
                uZ[0] = uY[0]; uY[0] = nu;
                su[0][y & 1][tid] = nu;
            }
            p1prev[0] = p1c;
        } else {
            float nu = (y <= IMG_H - 1) ? sig2(oh[0]) : 0.0f;
            uZ[0] = uY[0]; uY[0] = nu;
            su[0][y & 1][tid] = nu;
        }

        // ---- levels 1..D ----
#pragma unroll
        for (int l = 1; l <= D; ++l) {
            const int t = y - l;
            const int qlo = imax(r0 - (D - l) - HALO, 0);
            const bool qvalid = (t >= qlo) && (t <= IMG_H - 1);
            float qbase = (l == 1) ? (READQ ? qz : 0.0f) : qsave[l - 1];
            if (l >= 2) qsave[l - 1] = qvPrev;      // delayed save (read-before-write)
            float qv;
            if (qvalid) {
                const float uR = su[l - 1][t & 1][tid + 1];
                float gy = uY[l - 1] - uZ[l - 1];
                float gx = uR - uZ[l - 1];
                qv = fmaxf(qbase - 0.5f * (gy * v1h[l] + gx * v0h[l]), 0.0f);
            } else {
                qv = 0.0f;
            }

            if (l < D) {
                float p0p = v0h[l] * qv;
                float p1p = v1h[l] * qv;
                sp[l & 1][tid + 1] = p0p;
                __syncthreads();                   // barrier level l
                const int ulo = imax(r0 - (D - 1 - l) - HALO, 0);
                if (t >= ulo) {
                    float pm1 = sp[l & 1][tid];
                    float nu = (t <= IMG_H - 1)
                        ? sig2(oh[l] - (p1p - p1prev[l] + p0p - pm1)) : 0.0f;
                    uZ[l] = uY[l]; uY[l] = nu;
                    su[l][t & 1][tid] = nu;
                }
                p1prev[l] = p1p;
            } else {
                if constexpr (FINAL) {
                    float p0p = v0h[D] * qv;
                    float p1p = v1h[D] * qv;
                    sp[D & 1][tid + 1] = p0p;
                    __syncthreads();               // barrier final
                    if (t >= r0 && t < r0 + RPB) {
                        float pm1 = sp[D & 1][tid];
                        float Tq = p1p - p1prev[D] + p0p - pm1;
                        out[ibase + (size_t)t * IMG_W + tid] = 2.0f * (oh[D] - Tq);
                    }
                    p1prev[D] = p1p;
                } else {
                    if (t >= r0 && t < r0 + RPB)
                        out[ibase + (size_t)t * IMG_W + tid] = qv;
                }
            }
            qvPrev = qv;
        }
    }
}

extern "C" void kernel_launch(void* const* d_in, const int* in_sizes, int n_in,
                              void* d_out, int out_size, void* d_ws, size_t ws_size,
                              hipStream_t stream) {
    const float* o  = (const float*)d_in[0];
    const float* vf = (const float*)d_in[1];
    float* qA = (float*)d_ws;

    // iterations 1..5: o,vf -> q5  (no q read)
    k_pipe<5, false, false><<<NBLK, TPB, 0, stream>>>(o, vf, o, qA);
    // iterations 6..10 + final: q5,o,vf -> out
    k_pipe<5, true,  true ><<<NBLK, TPB, 0, stream>>>(qA, vf, o, (float*)d_out);
}